// Round 1
// baseline (65.900 us; speedup 1.0000x reference)
//
#include <hip/hip_runtime.h>

#define NSAMP 1024
#define NOBJ 25
#define NFEAT 64
#define D0 256

// ---------------------------------------------------------------------------
// K1: per-sample conv taps (A = xo@w0^T, B = xo@w1^T) + pairwise relu-pool.
// 1 block per sample, 256 threads (thread = output channel c).
// x tile (25*64 floats = 6.4KB) staged in LDS; all LDS reads are wave-uniform
// broadcasts (conflict-free). A[25]/B[25] live in registers.
// ---------------------------------------------------------------------------
__global__ __launch_bounds__(256) void conv_pairs_kernel(
    const float* __restrict__ x,    // (1024, 25*64)
    const float* __restrict__ w0,   // (256, 64)
    const float* __restrict__ w1,   // (256, 64)
    const float* __restrict__ cb,   // (256)
    float* __restrict__ h)          // (1024, 256)
{
  __shared__ float xs[NOBJ * NFEAT];
  const int n = blockIdx.x;
  const int c = threadIdx.x;

  {
    const float4* xg = reinterpret_cast<const float4*>(x + (size_t)n * (NOBJ * NFEAT));
    float4* xs4 = reinterpret_cast<float4*>(xs);
    for (int i = c; i < (NOBJ * NFEAT) / 4; i += 256) xs4[i] = xg[i];
  }
  __syncthreads();

  float A[NOBJ], B[NOBJ];
#pragma unroll
  for (int i = 0; i < NOBJ; ++i) { A[i] = 0.f; B[i] = 0.f; }

  const float* w0r = w0 + c * NFEAT;
  const float* w1r = w1 + c * NFEAT;

  // fc-chunked so each thread loads its w rows exactly once (32 float4 loads),
  // kept rolled (#pragma unroll 1) to stay icache-friendly; the 25-wide inner
  // loop gives 50 independent FMA chains.
#pragma unroll 1
  for (int fc = 0; fc < NFEAT; fc += 8) {
    const float4 wa0 = *reinterpret_cast<const float4*>(w0r + fc);
    const float4 wa1 = *reinterpret_cast<const float4*>(w0r + fc + 4);
    const float4 wb0 = *reinterpret_cast<const float4*>(w1r + fc);
    const float4 wb1 = *reinterpret_cast<const float4*>(w1r + fc + 4);
#pragma unroll
    for (int i = 0; i < NOBJ; ++i) {
      const float4 x0 = *reinterpret_cast<const float4*>(&xs[i * NFEAT + fc]);
      const float4 x1 = *reinterpret_cast<const float4*>(&xs[i * NFEAT + fc + 4]);
      A[i] += x0.x * wa0.x + x0.y * wa0.y + x0.z * wa0.z + x0.w * wa0.w
            + x1.x * wa1.x + x1.y * wa1.y + x1.z * wa1.z + x1.w * wa1.w;
      B[i] += x0.x * wb0.x + x0.y * wb0.y + x0.z * wb0.z + x0.w * wb0.w
            + x1.x * wb1.x + x1.y * wb1.y + x1.z * wb1.z + x1.w * wb1.w;
    }
  }

  const float bc = cb[c];
#pragma unroll
  for (int i = 0; i < NOBJ; ++i) A[i] += bc;  // fold conv bias into tap-0

  // all pairs (i, j=i+d), d=1..24: weight 1/(25-d), then /24.
  float hacc = 0.f;
#pragma unroll
  for (int d = 1; d < NOBJ; ++d) {
    float s = 0.f;
#pragma unroll
    for (int i = 0; i + d < NOBJ; ++i)
      s += fmaxf(A[i] + B[i + d], 0.f);
    hacc += s * (1.0f / (float)(NOBJ - d));
  }
  h[(size_t)n * D0 + c] = hacc * (1.0f / (float)(NOBJ - 1));
}

// ---------------------------------------------------------------------------
// K2/K3: out = [relu](in @ w^T + b), 1024x256 @ 256x256.
// ROWS rows per block, thread = output column; w row streamed as float4
// (L2-resident), input rows broadcast from LDS.
// ---------------------------------------------------------------------------
template <int ROWS, bool RELU>
__global__ __launch_bounds__(256) void linear_kernel(
    const float* __restrict__ in,   // (1024, 256)
    const float* __restrict__ w,    // (256, 256) [out][in]
    const float* __restrict__ b,    // (256)
    float* __restrict__ out)        // (1024, 256)
{
  __shared__ float hs[ROWS][256];
  const int m0 = blockIdx.x * ROWS;
  const int t = threadIdx.x;
#pragma unroll
  for (int r = 0; r < ROWS; ++r) hs[r][t] = in[(size_t)(m0 + r) * 256 + t];
  __syncthreads();

  float acc[ROWS];
#pragma unroll
  for (int r = 0; r < ROWS; ++r) acc[r] = 0.f;

  const float4* wr = reinterpret_cast<const float4*>(w + (size_t)t * 256);
#pragma unroll 4
  for (int q = 0; q < 64; ++q) {
    const float4 wv = wr[q];
#pragma unroll
    for (int r = 0; r < ROWS; ++r) {
      const float4 hv = *reinterpret_cast<const float4*>(&hs[r][q * 4]);
      acc[r] += hv.x * wv.x + hv.y * wv.y + hv.z * wv.z + hv.w * wv.w;
    }
  }
  const float bias = b[t];
#pragma unroll
  for (int r = 0; r < ROWS; ++r) {
    float v = acc[r] + bias;
    if (RELU) v = fmaxf(v, 0.f);
    out[(size_t)(m0 + r) * 256 + t] = v;
  }
}

// ---------------------------------------------------------------------------
// K4: out = in @ w3^T + b3, 1024x10, K=256. 16 rows/block, 16 threads/row
// (10 active). LDS padded to 264 floats/row -> 4-way worst-case conflicts.
// ---------------------------------------------------------------------------
__global__ __launch_bounds__(256) void final_kernel(
    const float* __restrict__ in,   // (1024, 256)
    const float* __restrict__ w3,   // (10, 256)
    const float* __restrict__ b3,   // (10)
    float* __restrict__ out)        // (1024, 10)
{
  __shared__ float hs[16][264];
  __shared__ float ws[10][264];
  const int m0 = blockIdx.x * 16;
  const int t = threadIdx.x;
  for (int i = t; i < 10 * 256; i += 256) ws[i >> 8][i & 255] = w3[i];
#pragma unroll
  for (int r = 0; r < 16; ++r) hs[r][t] = in[(size_t)(m0 + r) * 256 + t];
  __syncthreads();

  const int r = t >> 4, o = t & 15;
  if (o < 10) {
    float acc = 0.f;
#pragma unroll 8
    for (int q = 0; q < 64; ++q) {
      const float4 wv = *reinterpret_cast<const float4*>(&ws[o][q * 4]);
      const float4 hv = *reinterpret_cast<const float4*>(&hs[r][q * 4]);
      acc += hv.x * wv.x + hv.y * wv.y + hv.z * wv.z + hv.w * wv.w;
    }
    out[(size_t)(m0 + r) * 10 + o] = acc + b3[o];
  }
}

extern "C" void kernel_launch(void* const* d_in, const int* in_sizes, int n_in,
                              void* d_out, int out_size, void* d_ws, size_t ws_size,
                              hipStream_t stream) {
  const float* x   = (const float*)d_in[0];
  const float* cw0 = (const float*)d_in[1];
  const float* cw1 = (const float*)d_in[2];
  const float* cb  = (const float*)d_in[3];
  const float* w1  = (const float*)d_in[4];
  const float* b1  = (const float*)d_in[5];
  const float* w2  = (const float*)d_in[6];
  const float* b2  = (const float*)d_in[7];
  const float* w3  = (const float*)d_in[8];
  const float* b3  = (const float*)d_in[9];
  float* out = (float*)d_out;

  // workspace: h0 (1MB) + h1 (1MB), ping-pong (h2 reuses h0)
  float* h0 = (float*)d_ws;
  float* h1 = h0 + NSAMP * D0;

  conv_pairs_kernel<<<NSAMP, 256, 0, stream>>>(x, cw0, cw1, cb, h0);
  linear_kernel<4, true><<<NSAMP / 4, 256, 0, stream>>>(h0, w1, b1, h1);
  linear_kernel<4, true><<<NSAMP / 4, 256, 0, stream>>>(h1, w2, b2, h0);
  final_kernel<<<NSAMP / 16, 256, 0, stream>>>(h0, w3, b3, out);
}

// Round 2
// 43.796 us; speedup vs baseline: 1.5047x; 1.5047x over previous
//
#include <hip/hip_runtime.h>
#include <hip/hip_bf16.h>

#define NOBJ 25
#define D0 256

typedef short bf16x8 __attribute__((ext_vector_type(8)));
typedef short s16x4 __attribute__((ext_vector_type(4)));
typedef float f32x4 __attribute__((ext_vector_type(4)));

__device__ __forceinline__ short f2bf(float f) {
  __hip_bfloat16 b = __float2bfloat16(f);  // RTN
  return *reinterpret_cast<short*>(&b);
}

// ---------------------------------------------------------------------------
// prep: convert conv_w0|conv_w1 (256x64 f32 each) to bf16, concatenated.
// ---------------------------------------------------------------------------
__global__ __launch_bounds__(256) void prep_w(const float* __restrict__ w0,
                                              const float* __restrict__ w1,
                                              short* __restrict__ wb) {
  int i = blockIdx.x * 256 + threadIdx.x;  // 32768 total
  float v = (i < 16384) ? w0[i] : w1[i - 16384];
  wb[i] = f2bf(v);
}

// ---------------------------------------------------------------------------
// K1: per-sample A/B taps via bf16 MFMA + fused pairwise relu-pool.
// G=2 samples/block, 512 blocks x 256 threads (4 waves).
// Wave w owns channels [64w, 64w+64) for the MFMA phase (N-tiles 4w..4w+3);
// W-frags for both taps live in VGPRs (64), reused across both samples.
// A/B staged f32 in LDS [tap][25][260] (260-pad -> 2-way = free), pairwise
// phase: thread t = channel t, reads 50 f32, 300 relu-pairs in registers.
//
// mfma_f32_16x16x32_bf16 layouts (m89-verified C/D; AMD lab-notes A/B):
//   A: row = lane&15, k = 8*(lane>>4)+j  (8 contig bf16 -> 16B load)
//   B: col = lane&15, k = 8*(lane>>4)+j
//   D: col = lane&15, row = 4*(lane>>4)+reg
// ---------------------------------------------------------------------------
__global__ __launch_bounds__(256) void conv_pairs_mfma(
    const float* __restrict__ x,    // (1024, 25*64)
    const short* __restrict__ wb,   // (2, 256, 64) bf16
    const float* __restrict__ cb,   // (256)
    float* __restrict__ h)          // (1024, 256)
{
  __shared__ short xs[2][32][72];        // 9216 B, 72-pad -> 2-way frag reads
  __shared__ float ab[2][NOBJ][260];     // 52000 B
  const int t = threadIdx.x;
  const int lane = t & 63;
  const int wv = t >> 6;
  const int r = lane & 15;
  const int g = lane >> 4;
  const int n0 = blockIdx.x * 2;

  // W fragments, both taps, held across both samples.
  bf16x8 Wf[2][4][2];  // [tap][ntile][kstep]
#pragma unroll
  for (int tap = 0; tap < 2; ++tap)
#pragma unroll
    for (int ntl = 0; ntl < 4; ++ntl)
#pragma unroll
      for (int ks = 0; ks < 2; ++ks) {
        int ch = wv * 64 + ntl * 16 + r;
        Wf[tap][ntl][ks] = *reinterpret_cast<const bf16x8*>(
            wb + tap * 16384 + ch * 64 + ks * 32 + g * 8);
      }

  float cbv[4];
#pragma unroll
  for (int ntl = 0; ntl < 4; ++ntl) cbv[ntl] = cb[wv * 64 + ntl * 16 + r];

  // stage x (both samples) as bf16 into LDS
  for (int s = 0; s < 2; ++s) {
    const float4* xg = reinterpret_cast<const float4*>(x + (size_t)(n0 + s) * (NOBJ * 64));
    for (int i = t; i < 400; i += 256) {
      float4 v = xg[i];
      s16x4 p;
      p.x = f2bf(v.x); p.y = f2bf(v.y); p.z = f2bf(v.z); p.w = f2bf(v.w);
      *reinterpret_cast<s16x4*>(&xs[s][i >> 4][(i & 15) * 4]) = p;
    }
  }
  __syncthreads();

  for (int s = 0; s < 2; ++s) {
    // X fragments (rows 25..31 are garbage; their MFMA output rows are never read)
    bf16x8 Xf[2][2];  // [mtile][kstep]
#pragma unroll
    for (int mt = 0; mt < 2; ++mt)
#pragma unroll
      for (int ks = 0; ks < 2; ++ks)
        Xf[mt][ks] = *reinterpret_cast<const bf16x8*>(&xs[s][mt * 16 + r][ks * 32 + g * 8]);

    f32x4 acc[2][2][4];  // [tap][mtile][ntile]
#pragma unroll
    for (int tap = 0; tap < 2; ++tap)
#pragma unroll
      for (int mt = 0; mt < 2; ++mt)
#pragma unroll
        for (int ntl = 0; ntl < 4; ++ntl) {
          f32x4 z = {0.f, 0.f, 0.f, 0.f};
          acc[tap][mt][ntl] = z;
        }

#pragma unroll
    for (int tap = 0; tap < 2; ++tap)
#pragma unroll
      for (int mt = 0; mt < 2; ++mt)
#pragma unroll
        for (int ntl = 0; ntl < 4; ++ntl)
#pragma unroll
          for (int ks = 0; ks < 2; ++ks)
            acc[tap][mt][ntl] = __builtin_amdgcn_mfma_f32_16x16x32_bf16(
                Xf[mt][ks], Wf[tap][ntl][ks], acc[tap][mt][ntl], 0, 0, 0);

    // scatter to LDS (rows >= 25 dropped); conv bias folded into tap-0
#pragma unroll
    for (int tap = 0; tap < 2; ++tap)
#pragma unroll
      for (int mt = 0; mt < 2; ++mt)
#pragma unroll
        for (int ntl = 0; ntl < 4; ++ntl) {
          const int ch = wv * 64 + ntl * 16 + r;
          const int row0 = mt * 16 + g * 4;
          const float badd = (tap == 0) ? cbv[ntl] : 0.f;
#pragma unroll
          for (int q = 0; q < 4; ++q)
            if (row0 + q < NOBJ) ab[tap][row0 + q][ch] = acc[tap][mt][ntl][q] + badd;
        }
    __syncthreads();

    // pairwise relu-pool: thread t = channel t
    float A[NOBJ], Bv[NOBJ];
#pragma unroll
    for (int i = 0; i < NOBJ; ++i) { A[i] = ab[0][i][t]; Bv[i] = ab[1][i][t]; }
    float hacc = 0.f;
#pragma unroll
    for (int d = 1; d < NOBJ; ++d) {
      float sd = 0.f;
#pragma unroll
      for (int i = 0; i + d < NOBJ; ++i) sd += fmaxf(A[i] + Bv[i + d], 0.f);
      hacc += sd * (1.0f / (float)(NOBJ - d));
    }
    h[(size_t)(n0 + s) * D0 + t] = hacc * (1.0f / (float)(NOBJ - 1));
    __syncthreads();  // protect ab before next sample overwrites
  }
}

// ---------------------------------------------------------------------------
// K2: fused 3-layer MLP, fp32. 4 rows/block, 256 blocks x 256 threads.
// h rows ping-pong in padded LDS (264 -> rows land on distinct banks, 16B
// aligned); per-thread w row streamed as float4 (L1 retains the 128B lines
// across consecutive q -> no over-fetch).
// ---------------------------------------------------------------------------
__global__ __launch_bounds__(256) void mlp_kernel(
    const float* __restrict__ hin,  // (1024, 256)
    const float* __restrict__ w1, const float* __restrict__ b1,
    const float* __restrict__ w2, const float* __restrict__ b2,
    const float* __restrict__ w3, const float* __restrict__ b3,
    float* __restrict__ out)        // (1024, 10)
{
  __shared__ __align__(16) float hs[2][4][264];
  const int t = threadIdx.x;
  const int m0 = blockIdx.x * 4;

#pragma unroll
  for (int r = 0; r < 4; ++r) hs[0][r][t] = hin[(size_t)(m0 + r) * 256 + t];
  __syncthreads();

  // layer 1: hs[0] -> hs[1]
  {
    float acc[4];
#pragma unroll
    for (int r = 0; r < 4; ++r) acc[r] = b1[t];
    const float4* wr = reinterpret_cast<const float4*>(w1 + (size_t)t * 256);
#pragma unroll 4
    for (int q = 0; q < 64; ++q) {
      const float4 wv = wr[q];
#pragma unroll
      for (int r = 0; r < 4; ++r) {
        const float4 hv = *reinterpret_cast<const float4*>(&hs[0][r][q * 4]);
        acc[r] += hv.x * wv.x + hv.y * wv.y + hv.z * wv.z + hv.w * wv.w;
      }
    }
#pragma unroll
    for (int r = 0; r < 4; ++r) hs[1][r][t] = fmaxf(acc[r], 0.f);
  }
  __syncthreads();

  // layer 2: hs[1] -> hs[0]
  {
    float acc[4];
#pragma unroll
    for (int r = 0; r < 4; ++r) acc[r] = b2[t];
    const float4* wr = reinterpret_cast<const float4*>(w2 + (size_t)t * 256);
#pragma unroll 4
    for (int q = 0; q < 64; ++q) {
      const float4 wv = wr[q];
#pragma unroll
      for (int r = 0; r < 4; ++r) {
        const float4 hv = *reinterpret_cast<const float4*>(&hs[1][r][q * 4]);
        acc[r] += hv.x * wv.x + hv.y * wv.y + hv.z * wv.z + hv.w * wv.w;
      }
    }
#pragma unroll
    for (int r = 0; r < 4; ++r) hs[0][r][t] = fmaxf(acc[r], 0.f);
  }
  __syncthreads();

  // layer 3: hs[0] -> out, 40 dots (4 rows x 10 outs)
  if (t < 40) {
    const int r = t / 10, o = t % 10;
    float acc = b3[o];
    const float4* wr = reinterpret_cast<const float4*>(w3 + (size_t)o * 256);
#pragma unroll 8
    for (int q = 0; q < 64; ++q) {
      const float4 wv = wr[q];
      const float4 hv = *reinterpret_cast<const float4*>(&hs[0][r][q * 4]);
      acc += hv.x * wv.x + hv.y * wv.y + hv.z * wv.z + hv.w * wv.w;
    }
    out[(size_t)(m0 + r) * 10 + o] = acc;
  }
}

extern "C" void kernel_launch(void* const* d_in, const int* in_sizes, int n_in,
                              void* d_out, int out_size, void* d_ws, size_t ws_size,
                              hipStream_t stream) {
  const float* x   = (const float*)d_in[0];
  const float* cw0 = (const float*)d_in[1];
  const float* cw1 = (const float*)d_in[2];
  const float* cb  = (const float*)d_in[3];
  const float* w1  = (const float*)d_in[4];
  const float* b1  = (const float*)d_in[5];
  const float* w2  = (const float*)d_in[6];
  const float* b2  = (const float*)d_in[7];
  const float* w3  = (const float*)d_in[8];
  const float* b3  = (const float*)d_in[9];
  float* out = (float*)d_out;

  float* h  = (float*)d_ws;                        // 1 MB: (1024,256) f32
  short* wb = (short*)((char*)d_ws + (1 << 20));   // 64 KB: (2,256,64) bf16

  prep_w<<<128, 256, 0, stream>>>(cw0, cw1, wb);
  conv_pairs_mfma<<<512, 256, 0, stream>>>(x, wb, cb, h);
  mlp_kernel<<<256, 256, 0, stream>>>(h, w1, b1, w2, b2, w3, b3, out);
}